// Round 1
// baseline (2155.985 us; speedup 1.0000x reference)
//
#include <hip/hip_runtime.h>

#define NB 1024
#define NV 96
#define WW 128
#define EE 64
#define DD 64

typedef _Float16 h2t __attribute__((ext_vector_type(2)));
typedef float f2t __attribute__((ext_vector_type(2)));
typedef float f4t __attribute__((ext_vector_type(4)));

__device__ __forceinline__ float fdot2(h2t a, h2t b, float c) {
    return __builtin_amdgcn_fdot2(a, b, c, false);
}
__device__ __forceinline__ h2t pk2(float a, float b) {
    h2t r; r.x = (_Float16)a; r.y = (_Float16)b; return r;
}
__device__ __forceinline__ float tanh_f(float x) {
    float e = __expf(2.f * x);
    return 1.f - 2.f * __builtin_amdgcn_rcpf(e + 1.f);
}
__device__ __forceinline__ float sig_f(float x) {
    return __builtin_amdgcn_rcpf(1.f + __expf(-x));
}
__device__ __forceinline__ float wmax(float v) {
#pragma unroll
    for (int o = 32; o; o >>= 1) v = fmaxf(v, __shfl_xor(v, o, 64));
    return v;
}
__device__ __forceinline__ float wsum(float v) {
#pragma unroll
    for (int o = 32; o; o >>= 1) v += __shfl_xor(v, o, 64);
    return v;
}

__global__ __launch_bounds__(256, 2) void darnn_kernel(
    const float* __restrict__ x,
    const float* __restrict__ eWih, const float* __restrict__ eWhh,
    const float* __restrict__ ebih, const float* __restrict__ ebhh,
    const float* __restrict__ elv,  const float* __restrict__ elw,
    const float* __restrict__ elwb, const float* __restrict__ elu,
    const float* __restrict__ elub,
    const float* __restrict__ dWih, const float* __restrict__ dWhh,
    const float* __restrict__ dbih, const float* __restrict__ dbhh,
    const float* __restrict__ dlv,  const float* __restrict__ dlw,
    const float* __restrict__ dlwb, const float* __restrict__ dlu,
    const float* __restrict__ dlub, const float* __restrict__ dlp,
    const float* __restrict__ dlpb, const float* __restrict__ dly,
    const float* __restrict__ dlyb, const int* __restrict__ tgtp,
    float* __restrict__ out)
{
    __shared__ __align__(16) char  s_pool[96 * 65 * 4];   // u_e h2[96][65]  |  u_d h2[128][33]
    __shared__ __align__(16) float s_hseq[WW][EE];
    __shared__ __align__(16) float s_tmp[256];
    __shared__ __align__(16) float s_red[128];
    __shared__ __align__(16) float s_soft[128];
    __shared__ __align__(16) float s_wout[128];
    __shared__ __align__(16) float s_hc[128];
    __shared__ __align__(16) h2t   s_hch2[64];
    __shared__ __align__(16) float s_xcol[96];
    __shared__ __align__(16) h2t   s_xt[48];
    __shared__ __align__(16) float s_lv[128];
    __shared__ __align__(16) float s_y[128];
    __shared__ float s_scal[4];

    h2t (*s_ue)[65] = (h2t(*)[65])s_pool;
    h2t (*s_ud)[33] = (h2t(*)[33])s_pool;

    const int tid = threadIdx.x;
    const int b = blockIdx.x;
    const float* xb = x + (size_t)b * NV * WW;

    // ---------------- init ----------------
    if (tid < 128) { s_hc[tid] = 0.f; s_lv[tid] = elv[tid]; }
    if (tid < 64) s_hch2[tid] = pk2(0.f, 0.f);
    if (tid >= 96 && tid < 128) { s_red[tid] = -3e38f; s_soft[tid] = 0.f; }

    // ---------------- phase A: u_e[n][o] = sum_w x[b,n,w]*elu[o,w] + elub[o]
    {
        const int o = tid & 127, p = tid >> 7;
        float lu_r[64];
        {
            const f4t* lur = (const f4t*)(elu + o * WW + p * 64);
#pragma unroll
            for (int i = 0; i < 16; ++i) {
                f4t v = lur[i];
                lu_r[4*i] = v.x; lu_r[4*i+1] = v.y; lu_r[4*i+2] = v.z; lu_r[4*i+3] = v.w;
            }
        }
        float lub0 = 0.f, lub1 = 0.f;
        if (tid < 64) { lub0 = elub[2*tid]; lub1 = elub[2*tid+1]; }
        for (int n = 0; n < NV; ++n) {
            const f4t* xr = (const f4t*)(xb + n * WW + p * 64);
            float a = 0.f;
#pragma unroll
            for (int i = 0; i < 16; ++i) {
                f4t v = xr[i];
                a = fmaf(v.x, lu_r[4*i], a);   a = fmaf(v.y, lu_r[4*i+1], a);
                a = fmaf(v.z, lu_r[4*i+2], a); a = fmaf(v.w, lu_r[4*i+3], a);
            }
            s_tmp[tid] = a;
            __syncthreads();
            if (tid < 64) {
                float v0 = s_tmp[2*tid]   + s_tmp[128 + 2*tid]   + lub0;
                float v1 = s_tmp[2*tid+1] + s_tmp[128 + 2*tid+1] + lub1;
                s_ue[n][tid] = pk2(v0, v1);
            }
            __syncthreads();
        }
    }

    // ---------------- encoder weights -> fp16-pair registers
    h2t lw_r[32];
    {
        const float* r = elw + (tid & 127) * 128 + (tid >> 7) * 64;
#pragma unroll
        for (int i = 0; i < 32; ++i) { f2t v = *(const f2t*)(r + 2*i); lw_r[i] = pk2(v.x, v.y); }
    }
    const float lwb_r = (tid < 128) ? elwb[tid] : 0.f;
    h2t wih_r[48];
    {
        const float* r = eWih + tid * 96;
#pragma unroll
        for (int i = 0; i < 48; ++i) { f2t v = *(const f2t*)(r + 2*i); wih_r[i] = pk2(v.x, v.y); }
    }
    h2t whh_r[32];
    {
        const float* r = eWhh + tid * 64;
#pragma unroll
        for (int i = 0; i < 32; ++i) { f2t v = *(const f2t*)(r + 2*i); whh_r[i] = pk2(v.x, v.y); }
    }
    const float bsum_r = ebih[tid] + ebhh[tid];

    // ---------------- encoder recurrence ----------------
    for (int t = 0; t < WW; ++t) {
        float xv = 0.f;
        if (tid < NV) xv = xb[tid * WW + t];   // prefetch x column, consumed after softmax

        // (a) w_out[o] = hc . lw[o,:]
        {
            const int p = tid >> 7;
            float a = 0.f;
#pragma unroll
            for (int i = 0; i < 32; ++i) a = fdot2(s_hch2[p*32 + i], lw_r[i], a);
            s_tmp[tid] = a;
        }
        __syncthreads();
        if (tid < 128) s_wout[tid] = s_tmp[tid] + s_tmp[128 + tid] + lwb_r;
        __syncthreads();

        // (b) scores[n] = sum_w tanh(w_out[w] + u_e[n,w]) * lv[w]
        {
            float a = 0.f;
            if (tid < 192) {
                const int n = tid >> 1, prt = tid & 1;
#pragma unroll
                for (int j = 0; j < 32; ++j) {
                    const int wp = prt * 32 + j;
                    h2t u  = s_ue[n][wp];
                    f2t wo = *(const f2t*)&s_wout[2*wp];
                    f2t lv = *(const f2t*)&s_lv[2*wp];
                    a += tanh_f(wo.x + (float)u.x) * lv.x
                       + tanh_f(wo.y + (float)u.y) * lv.y;
                }
            }
            s_tmp[tid] = a;
        }
        __syncthreads();
        float sc = 0.f;
        if (tid < 96) { sc = s_tmp[2*tid] + s_tmp[2*tid+1]; s_red[tid] = sc; }
        __syncthreads();
        if (tid < 64) { float m = fmaxf(s_red[tid], s_red[tid+64]); m = wmax(m); if (!tid) s_scal[0] = m; }
        __syncthreads();
        if (tid < 96) { s_soft[tid] = __expf(sc - s_scal[0]); s_xcol[tid] = xv; }
        __syncthreads();
        if (tid < 64) { float s = s_soft[tid] + s_soft[tid+64]; s = wsum(s); if (!tid) s_scal[1] = __builtin_amdgcn_rcpf(s); }
        __syncthreads();
        if (tid < 48) {
            const float inv = s_scal[1];
            s_xt[tid] = pk2(s_soft[2*tid]   * inv * s_xcol[2*tid],
                            s_soft[2*tid+1] * inv * s_xcol[2*tid+1]);
        }
        __syncthreads();

        // (d) gates: g[j] = bih+bhh + x_tilde.Wih[j,:] + h.Whh[j,:]
        {
            float g = bsum_r;
#pragma unroll
            for (int i = 0; i < 48; ++i) g = fdot2(s_xt[i], wih_r[i], g);
#pragma unroll
            for (int i = 0; i < 32; ++i) g = fdot2(s_hch2[i], whh_r[i], g);
            s_tmp[tid] = g;
        }
        __syncthreads();

        // (e) LSTM state update
        if (tid < 64) {
            float gi = s_tmp[tid], gf = s_tmp[64+tid], gg = s_tmp[128+tid], go = s_tmp[192+tid];
            float c = sig_f(gf) * s_hc[64+tid] + sig_f(gi) * tanh_f(gg);
            float h = sig_f(go) * tanh_f(c);
            s_hc[tid] = h; s_hc[64+tid] = c;
            s_hseq[t][tid] = h;
            float hn = __shfl_xor(h, 1, 64), cn = __shfl_xor(c, 1, 64);
            if (!(tid & 1)) { s_hch2[tid>>1] = pk2(h, hn); s_hch2[32 + (tid>>1)] = pk2(c, cn); }
        }
        __syncthreads();
    }

    // ---------------- u_d[w][e2] = sum_e hseq[w][e]*dlu[e2,e] + dlub[e2]
    {
        const int e2h = tid & 31;
        const float lub0 = dlub[2*e2h], lub1 = dlub[2*e2h+1];
        const f4t* lur0 = (const f4t*)(dlu + (2*e2h)     * 64);
        const f4t* lur1 = (const f4t*)(dlu + (2*e2h + 1) * 64);
#pragma unroll 1
        for (int pass = 0; pass < 16; ++pass) {
            const int w = pass * 8 + (tid >> 5);
            float a0 = lub0, a1 = lub1;
#pragma unroll
            for (int i = 0; i < 16; ++i) {
                f4t l0 = lur0[i], l1 = lur1[i];
                f4t hv = *(const f4t*)&s_hseq[w][4*i];
                a0 = fmaf(hv.x, l0.x, a0); a0 = fmaf(hv.y, l0.y, a0);
                a0 = fmaf(hv.z, l0.z, a0); a0 = fmaf(hv.w, l0.w, a0);
                a1 = fmaf(hv.x, l1.x, a1); a1 = fmaf(hv.y, l1.y, a1);
                a1 = fmaf(hv.z, l1.z, a1); a1 = fmaf(hv.w, l1.w, a1);
            }
            s_ud[w][e2h] = pk2(a0, a1);
        }
    }

    // ---------------- decoder weights -> registers
    h2t dlw_r[16];
    {
        const float* r = dlw + (tid & 63) * 128 + (tid >> 6) * 32;
#pragma unroll
        for (int i = 0; i < 16; ++i) { f2t v = *(const f2t*)(r + 2*i); dlw_r[i] = pk2(v.x, v.y); }
    }
    const float dlwb_r = (tid < 64) ? dlwb[tid] : 0.f;
    h2t dwhh_r[32];
    {
        const float* r = dWhh + tid * 64;
#pragma unroll
        for (int i = 0; i < 32; ++i) { f2t v = *(const f2t*)(r + 2*i); dwhh_r[i] = pk2(v.x, v.y); }
    }
    const float dwih_r  = dWih[tid];
    const float dbsum_r = dbih[tid] + dbhh[tid];
    const float lp0     = dlp[0];
    const float lp1_r   = (tid < 64) ? dlp[1 + tid] : 0.f;
    const float lpb     = dlpb[0];
    const int   tgt     = tgtp[0];

    if (tid < 64)  s_lv[tid] = dlv[tid];
    if (tid < 128) { s_y[tid] = xb[tgt * WW + tid]; s_hc[tid] = 0.f; }
    if (tid < 64)  s_hch2[tid] = pk2(0.f, 0.f);
    __syncthreads();

    // ---------------- decoder recurrence ----------------
    for (int s = 0; s < WW - 1; ++s) {
        // (a') w_out_d[e2] = hc . dlw[e2,:]
        {
            const int p = tid >> 6;
            float a = 0.f;
#pragma unroll
            for (int i = 0; i < 16; ++i) a = fdot2(s_hch2[p*16 + i], dlw_r[i], a);
            s_tmp[tid] = a;
        }
        __syncthreads();
        if (tid < 64) s_wout[tid] = s_tmp[tid] + s_tmp[64+tid] + s_tmp[128+tid] + s_tmp[192+tid] + dlwb_r;
        __syncthreads();

        // (b') v[w] = sum_e tanh(w_out_d[e] + u_d[w,e]) * dlv[e]
        {
            const int w = tid & 127, prt = tid >> 7;
            float a = 0.f;
#pragma unroll
            for (int j = 0; j < 16; ++j) {
                const int ep = prt * 16 + j;
                h2t u  = s_ud[w][ep];
                f2t wo = *(const f2t*)&s_wout[2*ep];
                f2t lv = *(const f2t*)&s_lv[2*ep];
                a += tanh_f(wo.x + (float)u.x) * lv.x
                   + tanh_f(wo.y + (float)u.y) * lv.y;
            }
            s_tmp[tid] = a;
        }
        __syncthreads();
        float vv = 0.f;
        if (tid < 128) { vv = s_tmp[tid] + s_tmp[128+tid]; s_red[tid] = vv; }
        __syncthreads();
        if (tid < 64) { float m = fmaxf(s_red[tid], s_red[tid+64]); m = wmax(m); if (!tid) s_scal[0] = m; }
        __syncthreads();
        if (tid < 128) s_soft[tid] = __expf(vv - s_scal[0]);
        __syncthreads();
        if (tid < 64) { float sm = s_soft[tid] + s_soft[tid+64]; sm = wsum(sm); if (!tid) s_scal[1] = __builtin_amdgcn_rcpf(sm); }
        __syncthreads();

        // (c') context[e] = sum_w beta[w]*hseq[w][e]; then y_tilde (scalar)
        {
            const int e = tid & 63, p = tid >> 6;
            float a = 0.f;
#pragma unroll
            for (int j = 0; j < 32; ++j) { const int w = p*32 + j; a = fmaf(s_soft[w], s_hseq[w][e], a); }
            s_tmp[tid] = a;
        }
        __syncthreads();
        if (tid < 64) {
            float ctx  = (s_tmp[tid] + s_tmp[64+tid] + s_tmp[128+tid] + s_tmp[192+tid]) * s_scal[1];
            float term = ctx * lp1_r;
            term = wsum(term);
            if (!tid) s_scal[2] = term + s_y[s] * lp0 + lpb;
        }
        __syncthreads();

        // (d') gates
        {
            float g = dbsum_r + s_scal[2] * dwih_r;
#pragma unroll
            for (int i = 0; i < 32; ++i) g = fdot2(s_hch2[i], dwhh_r[i], g);
            s_tmp[tid] = g;
        }
        __syncthreads();

        // (e') LSTM state update
        if (tid < 64) {
            float gi = s_tmp[tid], gf = s_tmp[64+tid], gg = s_tmp[128+tid], go = s_tmp[192+tid];
            float c = sig_f(gf) * s_hc[64+tid] + sig_f(gi) * tanh_f(gg);
            float h = sig_f(go) * tanh_f(c);
            s_hc[tid] = h; s_hc[64+tid] = c;
            float hn = __shfl_xor(h, 1, 64), cn = __shfl_xor(c, 1, 64);
            if (!(tid & 1)) { s_hch2[tid>>1] = pk2(h, hn); s_hch2[32 + (tid>>1)] = pk2(c, cn); }
        }
        __syncthreads();
    }

    // ---------------- output: out[b] = [h,c] . dly + dlyb
    {
        float term = (tid < 128) ? s_hc[tid] * dly[tid] : 0.f;
        s_tmp[tid] = term;
        __syncthreads();
        if (tid < 64) {
            float v = s_tmp[tid] + s_tmp[64+tid] + s_tmp[128+tid] + s_tmp[192+tid];
            v = wsum(v);
            if (!tid) out[b] = v + dlyb[0];
        }
    }
}

extern "C" void kernel_launch(void* const* d_in, const int* in_sizes, int n_in,
                              void* d_out, int out_size, void* d_ws, size_t ws_size,
                              hipStream_t stream) {
    (void)in_sizes; (void)n_in; (void)d_ws; (void)ws_size; (void)out_size;
    const float* x    = (const float*)d_in[0];
    const float* eWih = (const float*)d_in[1];
    const float* eWhh = (const float*)d_in[2];
    const float* ebih = (const float*)d_in[3];
    const float* ebhh = (const float*)d_in[4];
    const float* elv  = (const float*)d_in[5];
    const float* elw  = (const float*)d_in[6];
    const float* elwb = (const float*)d_in[7];
    const float* elu  = (const float*)d_in[8];
    const float* elub = (const float*)d_in[9];
    const float* dWih = (const float*)d_in[10];
    const float* dWhh = (const float*)d_in[11];
    const float* dbih = (const float*)d_in[12];
    const float* dbhh = (const float*)d_in[13];
    const float* dlv  = (const float*)d_in[14];
    const float* dlw  = (const float*)d_in[15];
    const float* dlwb = (const float*)d_in[16];
    const float* dlu  = (const float*)d_in[17];
    const float* dlub = (const float*)d_in[18];
    const float* dlp  = (const float*)d_in[19];
    const float* dlpb = (const float*)d_in[20];
    const float* dly  = (const float*)d_in[21];
    const float* dlyb = (const float*)d_in[22];
    const int*   tgt  = (const int*)d_in[23];
    float* out = (float*)d_out;

    darnn_kernel<<<NB, 256, 0, stream>>>(
        x, eWih, eWhh, ebih, ebhh, elv, elw, elwb, elu, elub,
        dWih, dWhh, dbih, dbhh, dlv, dlw, dlwb, dlu, dlub,
        dlp, dlpb, dly, dlyb, tgt, out);
}